// Round 7
// baseline (824.867 us; speedup 1.0000x reference)
//
#include <hip/hip_runtime.h>
#include <hip/hip_bf16.h>

#define SEQ 2048

typedef unsigned short ushort_t;
typedef __attribute__((ext_vector_type(8))) short short8;
typedef __attribute__((ext_vector_type(4))) float f32x4;

__device__ __forceinline__ ushort_t f2bf(float f) {
    __hip_bfloat16 h = __float2bfloat16(f);
    return *reinterpret_cast<ushort_t*>(&h);
}

__device__ __forceinline__ void st(float* p, float v) { *p = v; }
__device__ __forceinline__ void st(ushort_t* p, float v) { *p = f2bf(v); }

// ---- staging helpers: global -> LDS bf16 [128][32] tile ----
__device__ __forceinline__ void stage_tile(ushort_t* dst, const float* src, int ld,
                                           int row0, int k0, int tid) {
#pragma unroll
    for (int c = 0; c < 4; ++c) {
        int flat = c * 256 + tid;          // 1024 float4 units
        int row = flat >> 3, col4 = flat & 7;
        float4 a = *(const float4*)&src[(size_t)(row0 + row) * ld + k0 + col4 * 4];
        union { ushort_t u[4]; unsigned long long ll; } pk;
        pk.u[0] = f2bf(a.x); pk.u[1] = f2bf(a.y);
        pk.u[2] = f2bf(a.z); pk.u[3] = f2bf(a.w);
        *(unsigned long long*)&dst[row * 32 + col4 * 4] = pk.ll;
    }
}
__device__ __forceinline__ void stage_tile(ushort_t* dst, const ushort_t* src, int ld,
                                           int row0, int k0, int tid) {
#pragma unroll
    for (int c = 0; c < 2; ++c) {
        int flat = c * 256 + tid;          // 512 short8 units
        int row = flat >> 2, col8 = flat & 3;
        *(short8*)&dst[row * 32 + col8 * 8] =
            *(const short8*)&src[(size_t)(row0 + row) * ld + k0 + col8 * 8];
    }
}

// C[M,N] = A[M,K] @ W[N,K]^T + bias[N]. bf16 MFMA, fp32 accumulate.
// 128x128 tile, 256 threads = 4 waves (2x2 of 64x64), BK=32.
template <typename TA, bool SILU, typename TC>
__global__ __launch_bounds__(256) void mfma_gemm_kernel(
    const TA* __restrict__ A, const float* __restrict__ W,
    const float* __restrict__ bias, TC* __restrict__ C, int M, int N, int Kd) {
    __shared__ __align__(16) ushort_t As[128 * 32];
    __shared__ __align__(16) ushort_t Bs[128 * 32];
    const int tid = threadIdx.x;
    const int w = tid >> 6, lane = tid & 63, l15 = lane & 15, quad = lane >> 4;
    const int m0 = blockIdx.y * 128, n0 = blockIdx.x * 128;
    const int rw = (w >> 1) * 64, cw = (w & 1) * 64;
    f32x4 acc[4][4];
#pragma unroll
    for (int mt = 0; mt < 4; ++mt)
#pragma unroll
        for (int nt = 0; nt < 4; ++nt) acc[mt][nt] = (f32x4){0.f, 0.f, 0.f, 0.f};

    for (int k0 = 0; k0 < Kd; k0 += 32) {
        stage_tile(As, A, Kd, m0, k0, tid);
        stage_tile(Bs, W, Kd, n0, k0, tid);
        __syncthreads();
        short8 af[4], bfr[4];
#pragma unroll
        for (int mt = 0; mt < 4; ++mt)
            af[mt] = *(const short8*)&As[(rw + mt * 16 + l15) * 32 + quad * 8];
#pragma unroll
        for (int nt = 0; nt < 4; ++nt)
            bfr[nt] = *(const short8*)&Bs[(cw + nt * 16 + l15) * 32 + quad * 8];
#pragma unroll
        for (int mt = 0; mt < 4; ++mt)
#pragma unroll
            for (int nt = 0; nt < 4; ++nt)
                acc[mt][nt] = __builtin_amdgcn_mfma_f32_16x16x32_bf16(
                    af[mt], bfr[nt], acc[mt][nt], 0, 0, 0);
        __syncthreads();
    }
#pragma unroll
    for (int nt = 0; nt < 4; ++nt) {
        int col = n0 + cw + nt * 16 + l15;
        float bb = bias[col];
#pragma unroll
        for (int mt = 0; mt < 4; ++mt)
#pragma unroll
            for (int r = 0; r < 4; ++r) {
                int row = m0 + rw + mt * 16 + quad * 4 + r;
                float v = acc[mt][nt][r] + bb;
                if (SILU) v = v / (1.f + __expf(-v));
                st(&C[(size_t)row * N + col], v);
            }
    }
}

// RoPE: read fp32 q (S x 1024, 8 heads) / k (S x 512, 4 heads), write rotated bf16.
__global__ void rope_bf_kernel(const float* __restrict__ qf, const float* __restrict__ kf,
                               ushort_t* __restrict__ qb, ushort_t* __restrict__ kb) {
    const int s = blockIdx.x;
    const float t = (float)s;
    for (int p = threadIdx.x; p < 768; p += 256) {
        int idx = p & 63;
        float invf = powf(10000.f, -(float)(2 * idx) / 128.f);
        float ang = t * invf;
        float c = cosf(ang), sn = sinf(ang);
        if (p < 512) {
            int h = p >> 6;
            const float* src = qf + (size_t)s * 1024 + h * 128 + idx;
            ushort_t* dst = qb + (size_t)s * 1024 + h * 128 + idx;
            float x1 = src[0], x2 = src[64];
            dst[0] = f2bf(x1 * c - x2 * sn);
            dst[64] = f2bf(x2 * c + x1 * sn);
        } else {
            int h = (p - 512) >> 6;
            const float* src = kf + (size_t)s * 512 + h * 128 + idx;
            ushort_t* dst = kb + (size_t)s * 512 + h * 128 + idx;
            float x1 = src[0], x2 = src[64];
            dst[0] = f2bf(x1 * c - x2 * sn);
            dst[64] = f2bf(x2 * c + x1 * sn);
        }
    }
}

// V [2048][512] bf16 -> V^T [512][2048] bf16, 64x64 LDS tiles.
__global__ void transpose_v_kernel(const ushort_t* __restrict__ v, ushort_t* __restrict__ vT) {
    __shared__ __align__(16) ushort_t t[64][72];
    const int s0 = blockIdx.x * 64, d0 = blockIdx.y * 64;
    const int tid = threadIdx.x;
#pragma unroll
    for (int it = 0; it < 2; ++it) {
        int u = tid + it * 256;
        int r = u >> 3, c8 = u & 7;
        *(short8*)&t[r][c8 * 8] = *(const short8*)&v[(size_t)(s0 + r) * 512 + d0 + c8 * 8];
    }
    __syncthreads();
#pragma unroll
    for (int it = 0; it < 2; ++it) {
        int u = tid + it * 256;
        int r = u >> 3, c8 = u & 7;  // r: output d-row, c8: chunk along s
        short8 o;
        ushort_t* op = (ushort_t*)&o;
#pragma unroll
        for (int i = 0; i < 8; ++i) op[i] = t[c8 * 8 + i][r];
        *(short8*)&vT[(size_t)(d0 + r) * 2048 + s0 + c8 * 8] = o;
    }
}

// MFMA flash attention, barrier-free. 1-D grid 1024: hg = lid&31 (h,g), qi = lid>>5.
// qt mapping: per-CU round-robin cosets {a, a+8, a+16, a+24} -> {2a, 2a+1, 30-2a, 31-2a},
// so every CU's 4 blocks sum to exactly 66 j-tiles (perfect balance).
// 4 waves; wave w owns q rows [w*16, w*16+16). P round-trips through per-wave LDS
// (same-wave DS ordering + explicit lgkmcnt fence); V^T fragments load直接 from global (L2).
__global__ __launch_bounds__(256) void mfma_attn_kernel(
    const ushort_t* __restrict__ qb, const ushort_t* __restrict__ kb,
    const ushort_t* __restrict__ vT, float* __restrict__ part) {
    const int lid = blockIdx.x;
    const int hg = lid & 31;
    const int h = hg >> 2, g = hg & 3;
    const int qi = lid >> 5;
    const int a = qi & 7, k2 = qi >> 3;
    const int qt = (k2 < 2) ? (2 * a + k2) : (28 + k2 - 2 * a);  // {2a,2a+1,30-2a,31-2a}
    const int i0 = qt * 64;
    const int tid = threadIdx.x;
    const int w = tid >> 6;
    const int lane = tid & 63;
    const int l15 = lane & 15;
    const int quad = lane >> 4;

    __shared__ __align__(16) ushort_t P_lds[4][16][72];  // per-wave P (9 KB total)

    const ushort_t* vtg = vT + (size_t)g * 128 * 2048;

    short8 aq[4];
    {
        const ushort_t* qrow = qb + (size_t)(i0 + w * 16 + l15) * 1024 + h * 128 + quad * 8;
#pragma unroll
        for (int kc = 0; kc < 4; ++kc) aq[kc] = *(const short8*)(qrow + kc * 32);
    }

    f32x4 oacc[8];
#pragma unroll
    for (int nt = 0; nt < 8; ++nt) oacc[nt] = (f32x4){0.f, 0.f, 0.f, 0.f};
    float m_st[4] = {-1e30f, -1e30f, -1e30f, -1e30f};
    float l_st[4] = {0.f, 0.f, 0.f, 0.f};

    for (int jt = 0; jt <= qt; ++jt) {
        const int j0 = jt * 64;
        // ---- prefetch V^T c=0 fragments (independent of QK/softmax) ----
        short8 vr0[8];
#pragma unroll
        for (int nt = 0; nt < 8; ++nt)
            vr0[nt] = *(const short8*)&vtg[(size_t)(nt * 16 + l15) * 2048 + j0 + quad * 8];
        // ---- S = Q K^T ----
        f32x4 sacc[4];
#pragma unroll
        for (int nt = 0; nt < 4; ++nt) sacc[nt] = (f32x4){0.f, 0.f, 0.f, 0.f};
#pragma unroll
        for (int nt = 0; nt < 4; ++nt) {
            const ushort_t* krow = kb + (size_t)(j0 + nt * 16 + l15) * 512 + g * 128 + quad * 8;
#pragma unroll
            for (int kc = 0; kc < 4; ++kc) {
                short8 bk = *(const short8*)(krow + kc * 32);
                sacc[nt] = __builtin_amdgcn_mfma_f32_16x16x32_bf16(aq[kc], bk, sacc[nt], 0, 0, 0);
            }
        }
        // ---- scale + causal mask (diagonal tile only) ----
#pragma unroll
        for (int nt = 0; nt < 4; ++nt)
#pragma unroll
            for (int r = 0; r < 4; ++r) sacc[nt][r] *= 0.08838834764831845f;
        if (jt == qt) {
#pragma unroll
            for (int nt = 0; nt < 4; ++nt) {
                int colg = nt * 16 + l15;
#pragma unroll
                for (int r = 0; r < 4; ++r) {
                    int rowg = w * 16 + quad * 4 + r;
                    if (colg > rowg) sacc[nt][r] = -1e30f;
                }
            }
        }
        // ---- online softmax (registers + 16-lane shuffles) ----
        float alpha[4];
#pragma unroll
        for (int r = 0; r < 4; ++r) {
            float mx = fmaxf(fmaxf(sacc[0][r], sacc[1][r]), fmaxf(sacc[2][r], sacc[3][r]));
            mx = fmaxf(mx, __shfl_xor(mx, 1));
            mx = fmaxf(mx, __shfl_xor(mx, 2));
            mx = fmaxf(mx, __shfl_xor(mx, 4));
            mx = fmaxf(mx, __shfl_xor(mx, 8));
            float mn = fmaxf(m_st[r], mx);
            alpha[r] = __expf(m_st[r] - mn);
            m_st[r] = mn;
        }
        float lsum[4] = {0.f, 0.f, 0.f, 0.f};
#pragma unroll
        for (int nt = 0; nt < 4; ++nt)
#pragma unroll
            for (int r = 0; r < 4; ++r) {
                float e = __expf(sacc[nt][r] - m_st[r]);
                sacc[nt][r] = e;
                lsum[r] += e;
            }
#pragma unroll
        for (int r = 0; r < 4; ++r) {
            float s = lsum[r];
            s += __shfl_xor(s, 1);
            s += __shfl_xor(s, 2);
            s += __shfl_xor(s, 4);
            s += __shfl_xor(s, 8);
            l_st[r] = l_st[r] * alpha[r] + s;
        }
        // ---- P -> per-wave LDS (bf16), rescale O ----
#pragma unroll
        for (int nt = 0; nt < 4; ++nt)
#pragma unroll
            for (int r = 0; r < 4; ++r)
                P_lds[w][quad * 4 + r][nt * 16 + l15] = f2bf(sacc[nt][r]);
#pragma unroll
        for (int nt = 0; nt < 8; ++nt)
#pragma unroll
            for (int r = 0; r < 4; ++r) oacc[nt][r] *= alpha[r];
        // same-wave DS write->read fence (no cross-wave hazard: P_lds is per-wave)
        asm volatile("s_waitcnt lgkmcnt(0)" ::: "memory");
        // ---- O += P V : c=0 from prefetched regs, c=1 direct from global ----
        {
            short8 ap0 = *(const short8*)&P_lds[w][l15][quad * 8];
#pragma unroll
            for (int nt = 0; nt < 8; ++nt)
                oacc[nt] = __builtin_amdgcn_mfma_f32_16x16x32_bf16(ap0, vr0[nt], oacc[nt], 0, 0, 0);
            short8 ap1 = *(const short8*)&P_lds[w][l15][32 + quad * 8];
#pragma unroll
            for (int nt = 0; nt < 8; ++nt) {
                short8 bv = *(const short8*)&vtg[(size_t)(nt * 16 + l15) * 2048 + j0 + 32 + quad * 8];
                oacc[nt] = __builtin_amdgcn_mfma_f32_16x16x32_bf16(ap1, bv, oacc[nt], 0, 0, 0);
            }
        }
    }
    // ---- normalize, write per-group partial ----
#pragma unroll
    for (int r = 0; r < 4; ++r) {
        float inv = 1.f / l_st[r];
        int row = i0 + w * 16 + quad * 4 + r;
        float* dst = part + ((size_t)g * SEQ + row) * 1024 + h * 128;
#pragma unroll
        for (int nt = 0; nt < 8; ++nt) dst[nt * 16 + l15] = oacc[nt][r] * inv;
    }
}

// attn_bf[s][c] = bf16( sum_g part[g][s][c] )
__global__ void sum4_bf_kernel(const float* __restrict__ part, ushort_t* __restrict__ attn) {
    int idx = blockIdx.x * 256 + threadIdx.x;  // 524288 float4 units
    const float4* p = (const float4*)part;
    float4 a = p[idx];
    float4 b = p[idx + 524288];
    float4 c = p[idx + 2 * 524288];
    float4 d = p[idx + 3 * 524288];
    union { ushort_t u[4]; unsigned long long ll; } pk;
    pk.u[0] = f2bf(a.x + b.x + c.x + d.x);
    pk.u[1] = f2bf(a.y + b.y + c.y + d.y);
    pk.u[2] = f2bf(a.z + b.z + c.z + d.z);
    pk.u[3] = f2bf(a.w + b.w + c.w + d.w);
    *(unsigned long long*)&attn[(size_t)idx * 4] = pk.ll;
}

extern "C" void kernel_launch(void* const* d_in, const int* in_sizes, int n_in,
                              void* d_out, int out_size, void* d_ws, size_t ws_size,
                              hipStream_t stream) {
    const float* x  = (const float*)d_in[0];
    const float* Wq = (const float*)d_in[1];
    const float* bq = (const float*)d_in[2];
    const float* Wk = (const float*)d_in[3];
    const float* bk = (const float*)d_in[4];
    const float* Wv = (const float*)d_in[5];
    const float* bv = (const float*)d_in[6];
    const float* Wo = (const float*)d_in[7];
    const float* bo = (const float*)d_in[8];
    const float* W1 = (const float*)d_in[9];
    const float* b1 = (const float*)d_in[10];
    const float* W2 = (const float*)d_in[11];
    const float* b2 = (const float*)d_in[12];
    float* out = (float*)d_out;

    // Workspace layout (MB offsets), 54 MB total:
    //  0-8   q_f32  (dead after rope)  -> 0-4 attn_bf, 4-8 o_bf
    //  8-12  k_f32  (dead after rope)
    // 12-14  v_bf
    // 14-18  q_bf
    // 18-20  k_bf
    // 20-52  part f32 (dead after sum4) -> 20-36 h1_bf
    // 52-54  vT (bf16, [4][128][2048])
    char* ws = (char*)d_ws;
    float*    q_f32   = (float*)(ws);
    float*    k_f32   = (float*)(ws + ((size_t)8 << 20));
    ushort_t* v_bf    = (ushort_t*)(ws + ((size_t)12 << 20));
    ushort_t* q_bf    = (ushort_t*)(ws + ((size_t)14 << 20));
    ushort_t* k_bf    = (ushort_t*)(ws + ((size_t)18 << 20));
    float*    part    = (float*)(ws + ((size_t)20 << 20));
    ushort_t* attn_bf = (ushort_t*)(ws);
    ushort_t* o_bf    = (ushort_t*)(ws + ((size_t)4 << 20));
    ushort_t* h1_bf   = (ushort_t*)(ws + ((size_t)20 << 20));
    ushort_t* vT      = (ushort_t*)(ws + ((size_t)52 << 20));

    // q/k/v projections (fp32 in, bf16 MFMA, fp32/bf16 out)
    mfma_gemm_kernel<float, false, float><<<dim3(8, 16), 256, 0, stream>>>(
        x, Wq, bq, q_f32, SEQ, 1024, 1024);
    mfma_gemm_kernel<float, false, float><<<dim3(4, 16), 256, 0, stream>>>(
        x, Wk, bk, k_f32, SEQ, 512, 1024);
    mfma_gemm_kernel<float, false, ushort_t><<<dim3(4, 16), 256, 0, stream>>>(
        x, Wv, bv, v_bf, SEQ, 512, 1024);
    // V -> V^T ; RoPE -> bf16 q,k
    transpose_v_kernel<<<dim3(32, 8), 256, 0, stream>>>(v_bf, vT);
    rope_bf_kernel<<<SEQ, 256, 0, stream>>>(q_f32, k_f32, q_bf, k_bf);
    // flash attention + group sum
    mfma_attn_kernel<<<1024, 256, 0, stream>>>(q_bf, k_bf, vT, part);
    sum4_bf_kernel<<<2048, 256, 0, stream>>>(part, attn_bf);
    // output projection -> bf16 o
    mfma_gemm_kernel<ushort_t, false, ushort_t><<<dim3(8, 16), 256, 0, stream>>>(
        attn_bf, Wo, bo, o_bf, SEQ, 1024, 1024);
    // MLP: W1+SiLU -> bf16 h1 ; W2 -> fp32 out
    mfma_gemm_kernel<ushort_t, true, ushort_t><<<dim3(32, 16), 256, 0, stream>>>(
        o_bf, W1, b1, h1_bf, SEQ, 4096, 1024);
    mfma_gemm_kernel<ushort_t, false, float><<<dim3(32, 16), 256, 0, stream>>>(
        h1_bf, W2, b2, out, SEQ, 4096, 4096);
}